// Round 12
// baseline (478.928 us; speedup 1.0000x reference)
//
#include <hip/hip_runtime.h>
#include <hip/hip_bf16.h>

// ---------------------------------------------------------------------------
// RGCN 2-layer forward, MI355X. Round 11 (= R10 with both gathers moved to
// 2-waves-per-row edge-interleaved form; R8-proven inner body; LDS combine):
//   L1: h = fb @ [W1|root1] (MFMA)  -> gather_h -> x1 in-place
//   L2: gather_x -> out = [xagg|x1] @ [W2stack;root2] + b2 (MFMA into d_out)
// N=50000, E=800000, IN=768, HID=OUT=128, R=8.
// ---------------------------------------------------------------------------

typedef __hip_bfloat16 bf16;
typedef __attribute__((ext_vector_type(4))) float f32x4;
typedef __attribute__((ext_vector_type(8))) short s16x8;

#define IN_DIM 768
#define NREL   8
#define NTL    9          // 8 relations + root
#define LDH    (NTL*128)  // 1152

__device__ __forceinline__ float bf2f(unsigned short u) {
    return __uint_as_float((unsigned)u << 16);
}
__device__ __forceinline__ unsigned short f2bf(float f) {
    __hip_bfloat16 b = __float2bfloat16(f);
    return *(unsigned short*)&b;
}

__device__ __forceinline__ void gload16(const void* g, void* l) {
    __builtin_amdgcn_global_load_lds(
        (const __attribute__((address_space(1))) void*)g,
        (__attribute__((address_space(3))) void*)l, 16, 0, 0);
}

// ----------------------------------------------- transform GEMM (layer 1) --
// (R4-proven) C[m, ntile*128+c] = A[M,K](bf16) @ BT[ntl*128, K]^T -> bf16
__global__ __launch_bounds__(256) void mfma_gemm(
    const bf16* __restrict__ A, int lda, const bf16* __restrict__ BT,
    bf16* __restrict__ C, int K, int nmt, int ntl)
{
    __shared__ bf16 Asm[128 * 64];
    __shared__ bf16 Bsm[128 * 64];

    const int tid  = threadIdx.x;
    const int lane = tid & 63;
    const int wrow = ((tid >> 7) & 1) * 64;
    const int wcol = ((tid >> 6) & 1) * 64;

    // bijective XCD-aware swizzle (m204)
    const int nwg  = nmt * ntl;
    const int orig = blockIdx.x;
    const int xcd  = orig & 7;
    const int q    = nwg >> 3, rr = nwg & 7;
    const int bse  = (xcd < rr) ? xcd * (q + 1) : rr * (q + 1) + (xcd - rr) * q;
    const int w    = bse + (orig >> 3);
    const int ntile = w % ntl;
    const int mtile = w / ntl;
    const long m0   = (long)mtile * 128;
    const bf16* Bp  = BT + (long)ntile * 128 * K;
    const int  ldh  = ntl * 128;
    const int  ncol0 = ntile * 128;

    f32x4 acc[4][4];
#pragma unroll
    for (int i = 0; i < 4; ++i)
#pragma unroll
        for (int j = 0; j < 4; ++j) acc[i][j] = (f32x4){0.f, 0.f, 0.f, 0.f};

    for (int k0 = 0; k0 < K; k0 += 64) {
#pragma unroll
        for (int i = 0; i < 4; ++i) {
            const int flat = i * 256 + tid;
            const int row  = flat >> 3;
            const int sch  = (flat & 7) ^ (row & 7);
            char* ldsA = (char*)Asm + (i * 256 + (tid & 192)) * 16;
            char* ldsB = (char*)Bsm + (i * 256 + (tid & 192)) * 16;
            gload16(A  + (m0 + row) * (long)lda + k0 + sch * 8, ldsA);
            gload16(Bp + (long)row * K          + k0 + sch * 8, ldsB);
        }
        __syncthreads();

#pragma unroll
        for (int ks = 0; ks < 2; ++ks) {
            s16x8 af[4], bfr[4];
            const int g = ks * 4 + (lane >> 4);
#pragma unroll
            for (int i = 0; i < 4; ++i) {
                const int ar = wrow + i * 16 + (lane & 15);
                af[i] = *(const s16x8*)((const char*)Asm + ar * 128 +
                                        (g ^ (ar & 7)) * 16);
                const int br = wcol + i * 16 + (lane & 15);
                bfr[i] = *(const s16x8*)((const char*)Bsm + br * 128 +
                                         (g ^ (br & 7)) * 16);
            }
#pragma unroll
            for (int i = 0; i < 4; ++i)
#pragma unroll
                for (int j = 0; j < 4; ++j)
                    acc[i][j] = __builtin_amdgcn_mfma_f32_16x16x32_bf16(
                        af[i], bfr[j], acc[i][j], 0, 0, 0);
        }
        __syncthreads();
    }

    // C/D layout: col=lane&15, row=(lane>>4)*4+reg (m89-verified)
#pragma unroll
    for (int i = 0; i < 4; ++i) {
#pragma unroll
        for (int r = 0; r < 4; ++r) {
            const long row = m0 + wrow + i * 16 + (lane >> 4) * 4 + r;
#pragma unroll
            for (int j = 0; j < 4; ++j) {
                const int col = wcol + j * 16 + (lane & 15);
                C[row * (long)ldh + ncol0 + col] =
                    __float2bfloat16(acc[i][j][r]);
            }
        }
    }
}

// ------------------------------------------- combine GEMM (layer 2 + out) --
// out[row, 768+col] = A[M,1152] @ BT[128,1152]^T + b2   (f32, guarded)
__global__ __launch_bounds__(256) void gemm_out(
    const bf16* __restrict__ A, const bf16* __restrict__ BT,
    const float* __restrict__ bias, float* __restrict__ out,
    int M, int K, int nmt)
{
    __shared__ bf16 Asm[128 * 64];
    __shared__ bf16 Bsm[128 * 64];

    const int tid  = threadIdx.x;
    const int lane = tid & 63;
    const int wrow = ((tid >> 7) & 1) * 64;
    const int wcol = ((tid >> 6) & 1) * 64;

    const int nwg  = nmt;
    const int orig = blockIdx.x;
    const int xcd  = orig & 7;
    const int q    = nwg >> 3, rr = nwg & 7;
    const int bse  = (xcd < rr) ? xcd * (q + 1) : rr * (q + 1) + (xcd - rr) * q;
    const int mtile = bse + (orig >> 3);
    const long m0   = (long)mtile * 128;

    f32x4 acc[4][4];
#pragma unroll
    for (int i = 0; i < 4; ++i)
#pragma unroll
        for (int j = 0; j < 4; ++j) acc[i][j] = (f32x4){0.f, 0.f, 0.f, 0.f};

    for (int k0 = 0; k0 < K; k0 += 64) {
#pragma unroll
        for (int i = 0; i < 4; ++i) {
            const int flat = i * 256 + tid;
            const int row  = flat >> 3;
            const int sch  = (flat & 7) ^ (row & 7);
            char* ldsA = (char*)Asm + (i * 256 + (tid & 192)) * 16;
            char* ldsB = (char*)Bsm + (i * 256 + (tid & 192)) * 16;
            gload16(A + (m0 + row) * (long)K + k0 + sch * 8, ldsA);
            gload16(BT + (long)row * K       + k0 + sch * 8, ldsB);
        }
        __syncthreads();

#pragma unroll
        for (int ks = 0; ks < 2; ++ks) {
            s16x8 af[4], bfr[4];
            const int g = ks * 4 + (lane >> 4);
#pragma unroll
            for (int i = 0; i < 4; ++i) {
                const int ar = wrow + i * 16 + (lane & 15);
                af[i] = *(const s16x8*)((const char*)Asm + ar * 128 +
                                        (g ^ (ar & 7)) * 16);
                const int br = wcol + i * 16 + (lane & 15);
                bfr[i] = *(const s16x8*)((const char*)Bsm + br * 128 +
                                         (g ^ (br & 7)) * 16);
            }
#pragma unroll
            for (int i = 0; i < 4; ++i)
#pragma unroll
                for (int j = 0; j < 4; ++j)
                    acc[i][j] = __builtin_amdgcn_mfma_f32_16x16x32_bf16(
                        af[i], bfr[j], acc[i][j], 0, 0, 0);
        }
        __syncthreads();
    }

    float breg[4];
#pragma unroll
    for (int j = 0; j < 4; ++j) breg[j] = bias[wcol + j * 16 + (lane & 15)];
#pragma unroll
    for (int i = 0; i < 4; ++i) {
#pragma unroll
        for (int r = 0; r < 4; ++r) {
            const long row = m0 + wrow + i * 16 + (lane >> 4) * 4 + r;
            if (row >= M) continue;
#pragma unroll
            for (int j = 0; j < 4; ++j) {
                const int col = wcol + j * 16 + (lane & 15);
                out[row * (long)(IN_DIM + 128) + IN_DIM + col] =
                    acc[i][j][r] + breg[j];
            }
        }
    }
}

// ------------------------------------------------------------- counts ----
__global__ __launch_bounds__(256) void rgcn_count(
    const int* __restrict__ edst, const int* __restrict__ etype, int E,
    float* __restrict__ counts)
{
    const int e = blockIdx.x * blockDim.x + threadIdx.x;
    if (e < E) atomicAdd(&counts[(long)edst[e] * NREL + etype[e]], 1.0f);
}

// ------------------------------------------------------------ CSR build ---
__global__ __launch_bounds__(256) void deg_block_scan(
    const float* __restrict__ counts, int N, int* __restrict__ rowstart,
    int* __restrict__ partials)
{
    __shared__ int s[256];
    const int d = blockIdx.x * 256 + threadIdx.x;
    int deg = 0;
    if (d < N) {
#pragma unroll
        for (int t = 0; t < NREL; ++t) deg += (int)counts[(long)d * NREL + t];
    }
    s[threadIdx.x] = deg;
    __syncthreads();
    for (int off = 1; off < 256; off <<= 1) {
        int v = (threadIdx.x >= off) ? s[threadIdx.x - off] : 0;
        __syncthreads();
        s[threadIdx.x] += v;
        __syncthreads();
    }
    if (d < N) rowstart[d] = s[threadIdx.x] - deg;
    if (threadIdx.x == 255) partials[blockIdx.x] = s[255];
}

__global__ __launch_bounds__(256) void scan_partials(int* partials, int nb)
{
    __shared__ int s[256];
    const int v = (threadIdx.x < nb) ? partials[threadIdx.x] : 0;
    s[threadIdx.x] = v;
    __syncthreads();
    for (int off = 1; off < 256; off <<= 1) {
        int u = (threadIdx.x >= off) ? s[threadIdx.x - off] : 0;
        __syncthreads();
        s[threadIdx.x] += u;
        __syncthreads();
    }
    if (threadIdx.x < nb) partials[threadIdx.x] = s[threadIdx.x] - v;
}

// also zeroes cursor (runs before csr_fill) — saves a memset launch
__global__ __launch_bounds__(256) void add_base(
    int* __restrict__ rowstart, const int* __restrict__ partials,
    int* __restrict__ cursor, int N, int E)
{
    const int d = blockIdx.x * 256 + threadIdx.x;
    if (d < N) {
        rowstart[d] += partials[blockIdx.x];
        cursor[d] = 0;
    }
    if (d == 0) rowstart[N] = E;
}

__global__ __launch_bounds__(256) void csr_fill(
    const int* __restrict__ esrc, const int* __restrict__ edst,
    const int* __restrict__ etype, int E, const int* __restrict__ rowstart,
    int* __restrict__ cursor, int* __restrict__ epack)
{
    const int e = blockIdx.x * 256 + threadIdx.x;
    if (e >= E) return;
    const int d = edst[e];
    const int pos = atomicAdd(&cursor[d], 1);
    epack[rowstart[d] + pos] = esrc[e] | (etype[e] << 24);
}

// -------------------------------------- layer-1 gather + fused epilogue ----
// 2 waves per dst row, edge-interleaved (wave sub handles pairs 4k+2*sub);
// R8-proven inner body; LDS combine; sub0 writes x1 = relu(agg+root+b1)
// in-place into h[wid, 1024:1152]. Block = 4 waves = 2 rows.
__global__ __launch_bounds__(256) void rgcn_gather_h(
    const int* __restrict__ rowstart, const int* __restrict__ epack,
    const float* __restrict__ counts, bf16* __restrict__ h,
    const float* __restrict__ b1, int N)
{
    __shared__ float xs[2][64][4];
    const int tid  = threadIdx.x;
    const int warp = tid >> 6;            // 0..3
    const int slot = warp >> 1;           // 0..1 (row within block)
    const int sub  = warp & 1;            // 0..1 (edge-interleave phase)
    const int wid  = blockIdx.x * 2 + slot;
    const int lane = tid & 63;
    const int half = lane >> 5;
    const int l32  = lane & 31;
    float a0 = 0.f, a1 = 0.f, a2 = 0.f, a3 = 0.f;
    const bool live = wid < N;            // no early return (barrier below)
    if (live) {
        const int start = rowstart[wid];
        const int end   = rowstart[wid + 1];
        const float nrm =
            1.0f / fmaxf(counts[(long)wid * NREL + (lane & 7)], 1.0f);
        for (int base = start; base < end; base += 64) {
            const int rem = end - base;
            const int cnt = rem < 64 ? rem : 64;
            int wv = 0;
            if (lane < cnt) wv = epack[base + lane];
            for (int i = sub * 2; i < cnt; i += 4) {
                const int  idx   = i + half;
                const bool valid = idx < cnt;
                const int  word  = __shfl(wv, idx);
                int src = 0, t = 0;
                if (valid) { src = word & 0xFFFFFF; t = ((unsigned)word) >> 24; }
                const float norm = __shfl(nrm, t);
                if (valid) {
                    const ushort4 raw = *(const ushort4*)(
                        h + (long)src * LDH + t * 128 + l32 * 4);
                    a0 += bf2f(raw.x) * norm;
                    a1 += bf2f(raw.y) * norm;
                    a2 += bf2f(raw.z) * norm;
                    a3 += bf2f(raw.w) * norm;
                }
            }
        }
    }
    // cross-wave combine: sub1 -> LDS, sync, sub0 adds
    if (sub == 1) {
        xs[slot][lane][0] = a0; xs[slot][lane][1] = a1;
        xs[slot][lane][2] = a2; xs[slot][lane][3] = a3;
    }
    __syncthreads();
    if (sub == 0 && live) {
        a0 += xs[slot][lane][0]; a1 += xs[slot][lane][1];
        a2 += xs[slot][lane][2]; a3 += xs[slot][lane][3];
        a0 += __shfl(a0, lane ^ 32);
        a1 += __shfl(a1, lane ^ 32);
        a2 += __shfl(a2, lane ^ 32);
        a3 += __shfl(a3, lane ^ 32);
        if (half == 0) {
            bf16* rp = h + (long)wid * LDH + NREL * 128 + l32 * 4;
            const ushort4 rt = *(const ushort4*)rp;
            const float4  bb = *(const float4*)(b1 + l32 * 4);
            ushort4 o;
            o.x = f2bf(fmaxf(a0 + bf2f(rt.x) + bb.x, 0.f));
            o.y = f2bf(fmaxf(a1 + bf2f(rt.y) + bb.y, 0.f));
            o.z = f2bf(fmaxf(a2 + bf2f(rt.z) + bb.z, 0.f));
            o.w = f2bf(fmaxf(a3 + bf2f(rt.w) + bb.w, 0.f));
            *(ushort4*)rp = o;
        }
    }
}

// ----------------------------- layer-2 gather (aggregate x1 per relation) --
// 2 waves per dst row, edge-interleaved; R8-proven inner body (static f32x4
// accums, deferred norm); LDS combine; sub0 writes xagg into xcat[:,0:1024].
__global__ __launch_bounds__(256) void rgcn_gather_x(
    const int* __restrict__ rowstart, const int* __restrict__ epack,
    const float* __restrict__ counts, bf16* __restrict__ xcat, int N)
{
    __shared__ float xs[2][64][32];       // 16 KB
    const int tid  = threadIdx.x;
    const int warp = tid >> 6;
    const int slot = warp >> 1;
    const int sub  = warp & 1;
    const int wid  = blockIdx.x * 2 + slot;
    const int lane = tid & 63;
    const int half = lane >> 5;
    const int l32  = lane & 31;
    f32x4 a0 = {0,0,0,0}, a1 = {0,0,0,0}, a2 = {0,0,0,0}, a3 = {0,0,0,0};
    f32x4 a4 = {0,0,0,0}, a5 = {0,0,0,0}, a6 = {0,0,0,0}, a7 = {0,0,0,0};
    const bool live = wid < N;
    float nrm = 1.0f;
    if (live) {
        nrm = 1.0f / fmaxf(counts[(long)wid * NREL + (lane & 7)], 1.0f);
        const int start = rowstart[wid];
        const int end   = rowstart[wid + 1];
        const bf16* x1 = xcat + NREL * 128;
        for (int base = start; base < end; base += 64) {
            const int rem = end - base;
            const int cnt = rem < 64 ? rem : 64;
            int wv = 0;
            if (lane < cnt) wv = epack[base + lane];
            for (int i = sub * 2; i < cnt; i += 4) {
                const int  idx   = i + half;
                const bool valid = idx < cnt;
                const int  word  = __shfl(wv, idx);
                if (valid) {
                    const int src = word & 0xFFFFFF;
                    const int t   = ((unsigned)word) >> 24;
                    const ushort4 raw =
                        *(const ushort4*)(x1 + (long)src * LDH + l32 * 4);
                    f32x4 v;
                    v[0] = bf2f(raw.x); v[1] = bf2f(raw.y);
                    v[2] = bf2f(raw.z); v[3] = bf2f(raw.w);
                    switch (t) {
                        case 0: a0 += v; break;
                        case 1: a1 += v; break;
                        case 2: a2 += v; break;
                        case 3: a3 += v; break;
                        case 4: a4 += v; break;
                        case 5: a5 += v; break;
                        case 6: a6 += v; break;
                        default: a7 += v; break;
                    }
                }
            }
        }
    }
    // cross-wave combine
    if (sub == 1) {
#define STORE4(T, AC)                                                        \
        { xs[slot][lane][T * 4 + 0] = AC[0]; xs[slot][lane][T * 4 + 1] = AC[1];\
          xs[slot][lane][T * 4 + 2] = AC[2]; xs[slot][lane][T * 4 + 3] = AC[3]; }
        STORE4(0, a0) STORE4(1, a1) STORE4(2, a2) STORE4(3, a3)
        STORE4(4, a4) STORE4(5, a5) STORE4(6, a6) STORE4(7, a7)
#undef STORE4
    }
    __syncthreads();
    if (sub == 0 && live) {
#define LOAD4(T, AC)                                                         \
        { AC[0] += xs[slot][lane][T * 4 + 0]; AC[1] += xs[slot][lane][T * 4 + 1];\
          AC[2] += xs[slot][lane][T * 4 + 2]; AC[3] += xs[slot][lane][T * 4 + 3]; }
        LOAD4(0, a0) LOAD4(1, a1) LOAD4(2, a2) LOAD4(3, a3)
        LOAD4(4, a4) LOAD4(5, a5) LOAD4(6, a6) LOAD4(7, a7)
#undef LOAD4
        bf16* op = xcat + (long)wid * LDH + l32 * 4;
#define EMIT(T, AC)                                                          \
        {                                                                    \
            f32x4 s = AC;                                                    \
            s[0] += __shfl(s[0], lane ^ 32); s[1] += __shfl(s[1], lane ^ 32);\
            s[2] += __shfl(s[2], lane ^ 32); s[3] += __shfl(s[3], lane ^ 32);\
            const float sc = __shfl(nrm, T);                                 \
            if (half == 0) {                                                 \
                ushort4 o;                                                   \
                o.x = f2bf(s[0] * sc); o.y = f2bf(s[1] * sc);                \
                o.z = f2bf(s[2] * sc); o.w = f2bf(s[3] * sc);                \
                *(ushort4*)(op + T * 128) = o;                               \
            }                                                                \
        }
        EMIT(0, a0) EMIT(1, a1) EMIT(2, a2) EMIT(3, a3)
        EMIT(4, a4) EMIT(5, a5) EMIT(6, a6) EMIT(7, a7)
#undef EMIT
    }
}

// -------------------------------------------- fused cvt + feature copy ----
__global__ __launch_bounds__(256) void cvt_copy(
    const float* __restrict__ f, bf16* __restrict__ fb,
    float* __restrict__ out, int N)
{
    const int idx = blockIdx.x * 256 + threadIdx.x;
    if (idx >= N * (IN_DIM / 8)) return;
    const int n  = idx / (IN_DIM / 8);
    const int k8 = (idx % (IN_DIM / 8)) << 3;
    const float4 a = *(const float4*)(f + (long)n * IN_DIM + k8);
    const float4 b = *(const float4*)(f + (long)n * IN_DIM + k8 + 4);
    float* op = out + (long)n * (IN_DIM + 128) + k8;
    *(float4*)op       = a;
    *(float4*)(op + 4) = b;
    bf16 o[8];
    o[0] = __float2bfloat16(a.x); o[1] = __float2bfloat16(a.y);
    o[2] = __float2bfloat16(a.z); o[3] = __float2bfloat16(a.w);
    o[4] = __float2bfloat16(b.x); o[5] = __float2bfloat16(b.y);
    o[6] = __float2bfloat16(b.z); o[7] = __float2bfloat16(b.w);
    *(s16x8*)(fb + (long)n * IN_DIM + k8) = *(const s16x8*)o;
}

// fused layer-1 weight conversion: wt [NTL][128][K] bf16 (BT layout);
// r<8 -> w1[r][k][n], r==8 -> root1[k][n]
__global__ __launch_bounds__(256) void cvt_w1m(
    const float* __restrict__ w1, const float* __restrict__ root1,
    bf16* __restrict__ wt, int K, long total)
{
    const long idx = (long)blockIdx.x * 256 + threadIdx.x;
    if (idx >= total) return;
    const int  k  = (int)(idx % K);
    const long rn = idx / K;
    const int  n  = (int)(rn & 127);
    const int  r  = (int)(rn >> 7);
    const float v = (r < NREL) ? w1[((long)r * K + k) * 128 + n]
                               : root1[(long)k * 128 + n];
    wt[idx] = __float2bfloat16(v);
}

// wcat[o, k] (BT layout [128][1152]): k<1024 -> w2[t=k>>7][c=k&127][o],
// else root2[k-1024][o]
__global__ __launch_bounds__(256) void cvt_wcat(
    const float* __restrict__ w2, const float* __restrict__ root2,
    bf16* __restrict__ wcat)
{
    const int idx = blockIdx.x * 256 + threadIdx.x;
    if (idx >= 128 * LDH) return;
    const int o = idx / LDH;
    const int k = idx % LDH;
    float v;
    if (k < NREL * 128) {
        const int t = k >> 7, c = k & 127;
        v = w2[((long)(t * 128 + c)) * 128 + o];
    } else {
        v = root2[(long)(k - NREL * 128) * 128 + o];
    }
    wcat[idx] = __float2bfloat16(v);
}

// ------------------------------------------------------------- launch ----
extern "C" void kernel_launch(void* const* d_in, const int* in_sizes, int n_in,
                              void* d_out, int out_size, void* d_ws,
                              size_t ws_size, hipStream_t stream)
{
    const float* feature = (const float*)d_in[0];
    const int*   eidx    = (const int*)d_in[1];
    const int*   etype   = (const int*)d_in[2];
    const float* w1      = (const float*)d_in[3];
    const float* root1   = (const float*)d_in[4];
    const float* b1      = (const float*)d_in[5];
    const float* w2      = (const float*)d_in[6];
    const float* root2   = (const float*)d_in[7];
    const float* b2      = (const float*)d_in[8];

    const int N = in_sizes[0] / IN_DIM;   // 50000
    const int E = in_sizes[2];            // 800000
    const int* esrc = eidx;
    const int* edst = eidx + E;
    const int NMT = (N + 127) / 128;      // 391
    const int NP  = NMT * 128;            // 50048

    char* p = (char*)d_ws;
    auto carve = [&](size_t b) { char* q = p; p += (b + 255) & ~(size_t)255; return q; };
    float* counts   = (float*)carve((size_t)N * NREL * 4);          // 1.6 MB
    bf16*  fb       = (bf16*)carve((size_t)NP * IN_DIM * 2);        // 76.9 MB
    bf16*  w1m      = (bf16*)carve((size_t)NTL * 128 * IN_DIM * 2); // 1.8 MB
    bf16*  wcat     = (bf16*)carve((size_t)128 * LDH * 2);          // 0.3 MB
    int*   rowstart = (int*)carve((size_t)(N + 1) * 4);
    int*   cursor   = (int*)carve((size_t)N * 4);
    int*   partials = (int*)carve(1024);
    int*   epack    = (int*)carve((size_t)E * 4);                   // 3.2 MB
    bf16*  h        = (bf16*)carve((size_t)NP * LDH * 2);           // 115.3 MB
    (void)ws_size;  // total ~200 MB; >=225 MB proven available in R2

    const int count_blks = (E + 255) / 256;
    const int nblk       = (N + 255) / 256;
    const int gat_blks   = (N + 1) / 2;            // 25000 (2 rows/block)
    const int gemm_blks  = NMT * NTL;              // 3519

    // conversions (feature cvt fused with out[:, :768] copy)
    cvt_copy<<<(N * (IN_DIM / 8) + 255) / 256, 256, 0, stream>>>(
        feature, fb, (float*)d_out, N);
    {
        const long t1 = (long)NTL * 128 * IN_DIM;
        cvt_w1m<<<(int)((t1 + 255) / 256), 256, 0, stream>>>(
            w1, root1, w1m, IN_DIM, t1);
        cvt_wcat<<<(128 * LDH + 255) / 256, 256, 0, stream>>>(w2, root2, wcat);
    }

    // counts + CSR (shared by both layers)
    hipMemsetAsync(counts, 0, (size_t)N * NREL * 4, stream);
    rgcn_count<<<count_blks, 256, 0, stream>>>(edst, etype, E, counts);
    deg_block_scan<<<nblk, 256, 0, stream>>>(counts, N, rowstart, partials);
    scan_partials<<<1, 256, 0, stream>>>(partials, nblk);
    add_base<<<nblk, 256, 0, stream>>>(rowstart, partials, cursor, N, E);
    csr_fill<<<count_blks, 256, 0, stream>>>(esrc, edst, etype, E,
                                             rowstart, cursor, epack);

    // ---------------- layer 1 ----------------
    mfma_gemm<<<gemm_blks, 256, 0, stream>>>(fb, IN_DIM, w1m, h,
                                             IN_DIM, NMT, NTL);
    rgcn_gather_h<<<gat_blks, 256, 0, stream>>>(rowstart, epack, counts,
                                                h, b1, N);

    // ---------------- layer 2 ----------------
    rgcn_gather_x<<<gat_blks, 256, 0, stream>>>(rowstart, epack, counts,
                                                h, N);
    gemm_out<<<NMT, 256, 0, stream>>>(h, wcat, b2, (float*)d_out, N,
                                      LDH, NMT);
}

// Round 13
// 421.695 us; speedup vs baseline: 1.1357x; 1.1357x over previous
//
#include <hip/hip_runtime.h>
#include <hip/hip_bf16.h>

// ---------------------------------------------------------------------------
// RGCN 2-layer forward, MI355X. Round 12 = exact restore of R10 (best proven:
// 421.9 us). R11's 2-waves-per-row gather regressed (redundant index traffic
// + barrier on critical path); gathers are L2/L3-BW-bound at their floor.
//   L1: h = fb @ [W1|root1] (MFMA)  -> gather_h (2-edge half-wave, fused
//       relu-epilogue) -> x1 in-place
//   L2: gather_x (2-edge half-wave, static f32x4 accums, deferred norm)
//       -> out = [xagg|x1] @ [W2stack;root2] + b2 (MFMA into d_out)
// N=50000, E=800000, IN=768, HID=OUT=128, R=8.
// ---------------------------------------------------------------------------

typedef __hip_bfloat16 bf16;
typedef __attribute__((ext_vector_type(4))) float f32x4;
typedef __attribute__((ext_vector_type(8))) short s16x8;

#define IN_DIM 768
#define NREL   8
#define NTL    9          // 8 relations + root
#define LDH    (NTL*128)  // 1152

__device__ __forceinline__ float bf2f(unsigned short u) {
    return __uint_as_float((unsigned)u << 16);
}
__device__ __forceinline__ unsigned short f2bf(float f) {
    __hip_bfloat16 b = __float2bfloat16(f);
    return *(unsigned short*)&b;
}

__device__ __forceinline__ void gload16(const void* g, void* l) {
    __builtin_amdgcn_global_load_lds(
        (const __attribute__((address_space(1))) void*)g,
        (__attribute__((address_space(3))) void*)l, 16, 0, 0);
}

// ----------------------------------------------- transform GEMM (layer 1) --
// (R4-proven) C[m, ntile*128+c] = A[M,K](bf16) @ BT[ntl*128, K]^T -> bf16
__global__ __launch_bounds__(256) void mfma_gemm(
    const bf16* __restrict__ A, int lda, const bf16* __restrict__ BT,
    bf16* __restrict__ C, int K, int nmt, int ntl)
{
    __shared__ bf16 Asm[128 * 64];
    __shared__ bf16 Bsm[128 * 64];

    const int tid  = threadIdx.x;
    const int lane = tid & 63;
    const int wrow = ((tid >> 7) & 1) * 64;
    const int wcol = ((tid >> 6) & 1) * 64;

    // bijective XCD-aware swizzle (m204)
    const int nwg  = nmt * ntl;
    const int orig = blockIdx.x;
    const int xcd  = orig & 7;
    const int q    = nwg >> 3, rr = nwg & 7;
    const int bse  = (xcd < rr) ? xcd * (q + 1) : rr * (q + 1) + (xcd - rr) * q;
    const int w    = bse + (orig >> 3);
    const int ntile = w % ntl;
    const int mtile = w / ntl;
    const long m0   = (long)mtile * 128;
    const bf16* Bp  = BT + (long)ntile * 128 * K;
    const int  ldh  = ntl * 128;
    const int  ncol0 = ntile * 128;

    f32x4 acc[4][4];
#pragma unroll
    for (int i = 0; i < 4; ++i)
#pragma unroll
        for (int j = 0; j < 4; ++j) acc[i][j] = (f32x4){0.f, 0.f, 0.f, 0.f};

    for (int k0 = 0; k0 < K; k0 += 64) {
#pragma unroll
        for (int i = 0; i < 4; ++i) {
            const int flat = i * 256 + tid;
            const int row  = flat >> 3;
            const int sch  = (flat & 7) ^ (row & 7);
            char* ldsA = (char*)Asm + (i * 256 + (tid & 192)) * 16;
            char* ldsB = (char*)Bsm + (i * 256 + (tid & 192)) * 16;
            gload16(A  + (m0 + row) * (long)lda + k0 + sch * 8, ldsA);
            gload16(Bp + (long)row * K          + k0 + sch * 8, ldsB);
        }
        __syncthreads();

#pragma unroll
        for (int ks = 0; ks < 2; ++ks) {
            s16x8 af[4], bfr[4];
            const int g = ks * 4 + (lane >> 4);
#pragma unroll
            for (int i = 0; i < 4; ++i) {
                const int ar = wrow + i * 16 + (lane & 15);
                af[i] = *(const s16x8*)((const char*)Asm + ar * 128 +
                                        (g ^ (ar & 7)) * 16);
                const int br = wcol + i * 16 + (lane & 15);
                bfr[i] = *(const s16x8*)((const char*)Bsm + br * 128 +
                                         (g ^ (br & 7)) * 16);
            }
#pragma unroll
            for (int i = 0; i < 4; ++i)
#pragma unroll
                for (int j = 0; j < 4; ++j)
                    acc[i][j] = __builtin_amdgcn_mfma_f32_16x16x32_bf16(
                        af[i], bfr[j], acc[i][j], 0, 0, 0);
        }
        __syncthreads();
    }

    // C/D layout: col=lane&15, row=(lane>>4)*4+reg (m89-verified)
#pragma unroll
    for (int i = 0; i < 4; ++i) {
#pragma unroll
        for (int r = 0; r < 4; ++r) {
            const long row = m0 + wrow + i * 16 + (lane >> 4) * 4 + r;
#pragma unroll
            for (int j = 0; j < 4; ++j) {
                const int col = wcol + j * 16 + (lane & 15);
                C[row * (long)ldh + ncol0 + col] =
                    __float2bfloat16(acc[i][j][r]);
            }
        }
    }
}

// ------------------------------------------- combine GEMM (layer 2 + out) --
// out[row, 768+col] = A[M,1152] @ BT[128,1152]^T + b2   (f32, guarded)
__global__ __launch_bounds__(256) void gemm_out(
    const bf16* __restrict__ A, const bf16* __restrict__ BT,
    const float* __restrict__ bias, float* __restrict__ out,
    int M, int K, int nmt)
{
    __shared__ bf16 Asm[128 * 64];
    __shared__ bf16 Bsm[128 * 64];

    const int tid  = threadIdx.x;
    const int lane = tid & 63;
    const int wrow = ((tid >> 7) & 1) * 64;
    const int wcol = ((tid >> 6) & 1) * 64;

    const int nwg  = nmt;
    const int orig = blockIdx.x;
    const int xcd  = orig & 7;
    const int q    = nwg >> 3, rr = nwg & 7;
    const int bse  = (xcd < rr) ? xcd * (q + 1) : rr * (q + 1) + (xcd - rr) * q;
    const int mtile = bse + (orig >> 3);
    const long m0   = (long)mtile * 128;

    f32x4 acc[4][4];
#pragma unroll
    for (int i = 0; i < 4; ++i)
#pragma unroll
        for (int j = 0; j < 4; ++j) acc[i][j] = (f32x4){0.f, 0.f, 0.f, 0.f};

    for (int k0 = 0; k0 < K; k0 += 64) {
#pragma unroll
        for (int i = 0; i < 4; ++i) {
            const int flat = i * 256 + tid;
            const int row  = flat >> 3;
            const int sch  = (flat & 7) ^ (row & 7);
            char* ldsA = (char*)Asm + (i * 256 + (tid & 192)) * 16;
            char* ldsB = (char*)Bsm + (i * 256 + (tid & 192)) * 16;
            gload16(A + (m0 + row) * (long)K + k0 + sch * 8, ldsA);
            gload16(BT + (long)row * K       + k0 + sch * 8, ldsB);
        }
        __syncthreads();

#pragma unroll
        for (int ks = 0; ks < 2; ++ks) {
            s16x8 af[4], bfr[4];
            const int g = ks * 4 + (lane >> 4);
#pragma unroll
            for (int i = 0; i < 4; ++i) {
                const int ar = wrow + i * 16 + (lane & 15);
                af[i] = *(const s16x8*)((const char*)Asm + ar * 128 +
                                        (g ^ (ar & 7)) * 16);
                const int br = wcol + i * 16 + (lane & 15);
                bfr[i] = *(const s16x8*)((const char*)Bsm + br * 128 +
                                         (g ^ (br & 7)) * 16);
            }
#pragma unroll
            for (int i = 0; i < 4; ++i)
#pragma unroll
                for (int j = 0; j < 4; ++j)
                    acc[i][j] = __builtin_amdgcn_mfma_f32_16x16x32_bf16(
                        af[i], bfr[j], acc[i][j], 0, 0, 0);
        }
        __syncthreads();
    }

    float breg[4];
#pragma unroll
    for (int j = 0; j < 4; ++j) breg[j] = bias[wcol + j * 16 + (lane & 15)];
#pragma unroll
    for (int i = 0; i < 4; ++i) {
#pragma unroll
        for (int r = 0; r < 4; ++r) {
            const long row = m0 + wrow + i * 16 + (lane >> 4) * 4 + r;
            if (row >= M) continue;
#pragma unroll
            for (int j = 0; j < 4; ++j) {
                const int col = wcol + j * 16 + (lane & 15);
                out[row * (long)(IN_DIM + 128) + IN_DIM + col] =
                    acc[i][j][r] + breg[j];
            }
        }
    }
}

// ------------------------------------------------------------- counts ----
__global__ __launch_bounds__(256) void rgcn_count(
    const int* __restrict__ edst, const int* __restrict__ etype, int E,
    float* __restrict__ counts)
{
    const int e = blockIdx.x * blockDim.x + threadIdx.x;
    if (e < E) atomicAdd(&counts[(long)edst[e] * NREL + etype[e]], 1.0f);
}

// ------------------------------------------------------------ CSR build ---
__global__ __launch_bounds__(256) void deg_block_scan(
    const float* __restrict__ counts, int N, int* __restrict__ rowstart,
    int* __restrict__ partials)
{
    __shared__ int s[256];
    const int d = blockIdx.x * 256 + threadIdx.x;
    int deg = 0;
    if (d < N) {
#pragma unroll
        for (int t = 0; t < NREL; ++t) deg += (int)counts[(long)d * NREL + t];
    }
    s[threadIdx.x] = deg;
    __syncthreads();
    for (int off = 1; off < 256; off <<= 1) {
        int v = (threadIdx.x >= off) ? s[threadIdx.x - off] : 0;
        __syncthreads();
        s[threadIdx.x] += v;
        __syncthreads();
    }
    if (d < N) rowstart[d] = s[threadIdx.x] - deg;
    if (threadIdx.x == 255) partials[blockIdx.x] = s[255];
}

__global__ __launch_bounds__(256) void scan_partials(int* partials, int nb)
{
    __shared__ int s[256];
    const int v = (threadIdx.x < nb) ? partials[threadIdx.x] : 0;
    s[threadIdx.x] = v;
    __syncthreads();
    for (int off = 1; off < 256; off <<= 1) {
        int u = (threadIdx.x >= off) ? s[threadIdx.x - off] : 0;
        __syncthreads();
        s[threadIdx.x] += u;
        __syncthreads();
    }
    if (threadIdx.x < nb) partials[threadIdx.x] = s[threadIdx.x] - v;
}

// also zeroes cursor (runs before csr_fill) — saves a memset launch
__global__ __launch_bounds__(256) void add_base(
    int* __restrict__ rowstart, const int* __restrict__ partials,
    int* __restrict__ cursor, int N, int E)
{
    const int d = blockIdx.x * 256 + threadIdx.x;
    if (d < N) {
        rowstart[d] += partials[blockIdx.x];
        cursor[d] = 0;
    }
    if (d == 0) rowstart[N] = E;
}

__global__ __launch_bounds__(256) void csr_fill(
    const int* __restrict__ esrc, const int* __restrict__ edst,
    const int* __restrict__ etype, int E, const int* __restrict__ rowstart,
    int* __restrict__ cursor, int* __restrict__ epack)
{
    const int e = blockIdx.x * 256 + threadIdx.x;
    if (e >= E) return;
    const int d = edst[e];
    const int pos = atomicAdd(&cursor[d], 1);
    epack[rowstart[d] + pos] = esrc[e] | (etype[e] << 24);
}

// -------------------------------------- layer-1 gather + fused epilogue ----
// (R4/R8-proven) one wave per dst row (<N); 2 edges/iter; writes
// x1 = relu(agg+root+b1) in-place into h[wid, 1024:1152].
__global__ __launch_bounds__(256) void rgcn_gather_h(
    const int* __restrict__ rowstart, const int* __restrict__ epack,
    const float* __restrict__ counts, bf16* __restrict__ h,
    const float* __restrict__ b1, int N)
{
    const int wid  = (blockIdx.x * 256 + threadIdx.x) >> 6;
    if (wid >= N) return;
    const int lane = threadIdx.x & 63;
    const int half = lane >> 5;
    const int l32  = lane & 31;
    float a0 = 0.f, a1 = 0.f, a2 = 0.f, a3 = 0.f;
    const int start = rowstart[wid];
    const int end   = rowstart[wid + 1];
    const float nrm =
        1.0f / fmaxf(counts[(long)wid * NREL + (lane & 7)], 1.0f);
    for (int base = start; base < end; base += 64) {
        const int rem = end - base;
        const int cnt = rem < 64 ? rem : 64;
        int wv = 0;
        if (lane < cnt) wv = epack[base + lane];
        for (int i = 0; i < cnt; i += 2) {
            const int  idx   = i + half;
            const bool valid = idx < cnt;
            const int  word  = __shfl(wv, idx);
            int src = 0, t = 0;
            if (valid) { src = word & 0xFFFFFF; t = ((unsigned)word) >> 24; }
            const float norm = __shfl(nrm, t);
            if (valid) {
                const ushort4 raw = *(const ushort4*)(
                    h + (long)src * LDH + t * 128 + l32 * 4);
                a0 += bf2f(raw.x) * norm;
                a1 += bf2f(raw.y) * norm;
                a2 += bf2f(raw.z) * norm;
                a3 += bf2f(raw.w) * norm;
            }
        }
    }
    a0 += __shfl(a0, lane ^ 32);
    a1 += __shfl(a1, lane ^ 32);
    a2 += __shfl(a2, lane ^ 32);
    a3 += __shfl(a3, lane ^ 32);
    if (half == 0) {
        bf16* rp = h + (long)wid * LDH + NREL * 128 + l32 * 4;
        const ushort4 rt = *(const ushort4*)rp;
        const float4  bb = *(const float4*)(b1 + l32 * 4);
        ushort4 o;
        o.x = f2bf(fmaxf(a0 + bf2f(rt.x) + bb.x, 0.f));
        o.y = f2bf(fmaxf(a1 + bf2f(rt.y) + bb.y, 0.f));
        o.z = f2bf(fmaxf(a2 + bf2f(rt.z) + bb.z, 0.f));
        o.w = f2bf(fmaxf(a3 + bf2f(rt.w) + bb.w, 0.f));
        *(ushort4*)rp = o;
    }
}

// ----------------------------- layer-2 gather (aggregate x1 per relation) --
// (R8-proven) one wave per dst row (<N); 2 edges/iter (32 lanes x ushort4);
// raw per-relation sums in 8 static f32x4 regs; norm deferred to store.
// reads x1 = xcat[:,1024:1152]; writes xagg into xcat[:,0:1024].
__global__ __launch_bounds__(256) void rgcn_gather_x(
    const int* __restrict__ rowstart, const int* __restrict__ epack,
    const float* __restrict__ counts, bf16* __restrict__ xcat, int N)
{
    const int wid  = (blockIdx.x * 256 + threadIdx.x) >> 6;
    if (wid >= N) return;
    const int lane = threadIdx.x & 63;
    const int half = lane >> 5;
    const int l32  = lane & 31;
    f32x4 a0 = {0,0,0,0}, a1 = {0,0,0,0}, a2 = {0,0,0,0}, a3 = {0,0,0,0};
    f32x4 a4 = {0,0,0,0}, a5 = {0,0,0,0}, a6 = {0,0,0,0}, a7 = {0,0,0,0};
    const float nrm =
        1.0f / fmaxf(counts[(long)wid * NREL + (lane & 7)], 1.0f);
    const int start = rowstart[wid];
    const int end   = rowstart[wid + 1];
    const bf16* x1 = xcat + NREL * 128;
    for (int base = start; base < end; base += 64) {
        const int rem = end - base;
        const int cnt = rem < 64 ? rem : 64;
        int wv = 0;
        if (lane < cnt) wv = epack[base + lane];
        for (int i = 0; i < cnt; i += 2) {
            const int  idx   = i + half;          // <= 63 always
            const bool valid = idx < cnt;
            const int  word  = __shfl(wv, idx);   // lanes>=cnt hold 0
            if (valid) {
                const int src = word & 0xFFFFFF;
                const int t   = ((unsigned)word) >> 24;
                const ushort4 raw =
                    *(const ushort4*)(x1 + (long)src * LDH + l32 * 4);
                f32x4 v;
                v[0] = bf2f(raw.x); v[1] = bf2f(raw.y);
                v[2] = bf2f(raw.z); v[3] = bf2f(raw.w);
                switch (t) {
                    case 0: a0 += v; break;
                    case 1: a1 += v; break;
                    case 2: a2 += v; break;
                    case 3: a3 += v; break;
                    case 4: a4 += v; break;
                    case 5: a5 += v; break;
                    case 6: a6 += v; break;
                    default: a7 += v; break;
                }
            }
        }
    }
    bf16* op = xcat + (long)wid * LDH + l32 * 4;
#define EMIT(T, AC)                                                          \
    {                                                                        \
        f32x4 s = AC;                                                        \
        s[0] += __shfl(s[0], lane ^ 32); s[1] += __shfl(s[1], lane ^ 32);    \
        s[2] += __shfl(s[2], lane ^ 32); s[3] += __shfl(s[3], lane ^ 32);    \
        const float sc = __shfl(nrm, T);                                     \
        if (half == 0) {                                                     \
            ushort4 o;                                                       \
            o.x = f2bf(s[0] * sc); o.y = f2bf(s[1] * sc);                    \
            o.z = f2bf(s[2] * sc); o.w = f2bf(s[3] * sc);                    \
            *(ushort4*)(op + T * 128) = o;                                   \
        }                                                                    \
    }
    EMIT(0, a0) EMIT(1, a1) EMIT(2, a2) EMIT(3, a3)
    EMIT(4, a4) EMIT(5, a5) EMIT(6, a6) EMIT(7, a7)
#undef EMIT
}

// -------------------------------------------- fused cvt + feature copy ----
__global__ __launch_bounds__(256) void cvt_copy(
    const float* __restrict__ f, bf16* __restrict__ fb,
    float* __restrict__ out, int N)
{
    const int idx = blockIdx.x * 256 + threadIdx.x;
    if (idx >= N * (IN_DIM / 8)) return;
    const int n  = idx / (IN_DIM / 8);
    const int k8 = (idx % (IN_DIM / 8)) << 3;
    const float4 a = *(const float4*)(f + (long)n * IN_DIM + k8);
    const float4 b = *(const float4*)(f + (long)n * IN_DIM + k8 + 4);
    float* op = out + (long)n * (IN_DIM + 128) + k8;
    *(float4*)op       = a;
    *(float4*)(op + 4) = b;
    bf16 o[8];
    o[0] = __float2bfloat16(a.x); o[1] = __float2bfloat16(a.y);
    o[2] = __float2bfloat16(a.z); o[3] = __float2bfloat16(a.w);
    o[4] = __float2bfloat16(b.x); o[5] = __float2bfloat16(b.y);
    o[6] = __float2bfloat16(b.z); o[7] = __float2bfloat16(b.w);
    *(s16x8*)(fb + (long)n * IN_DIM + k8) = *(const s16x8*)o;
}

// fused layer-1 weight conversion: wt [NTL][128][K] bf16 (BT layout);
// r<8 -> w1[r][k][n], r==8 -> root1[k][n]
__global__ __launch_bounds__(256) void cvt_w1m(
    const float* __restrict__ w1, const float* __restrict__ root1,
    bf16* __restrict__ wt, int K, long total)
{
    const long idx = (long)blockIdx.x * 256 + threadIdx.x;
    if (idx >= total) return;
    const int  k  = (int)(idx % K);
    const long rn = idx / K;
    const int  n  = (int)(rn & 127);
    const int  r  = (int)(rn >> 7);
    const float v = (r < NREL) ? w1[((long)r * K + k) * 128 + n]
                               : root1[(long)k * 128 + n];
    wt[idx] = __float2bfloat16(v);
}

// wcat[o, k] (BT layout [128][1152]): k<1024 -> w2[t=k>>7][c=k&127][o],
// else root2[k-1024][o]
__global__ __launch_bounds__(256) void cvt_wcat(
    const float* __restrict__ w2, const float* __restrict__ root2,
    bf16* __restrict__ wcat)
{
    const int idx = blockIdx.x * 256 + threadIdx.x;
    if (idx >= 128 * LDH) return;
    const int o = idx / LDH;
    const int k = idx % LDH;
    float v;
    if (k < NREL * 128) {
        const int t = k >> 7, c = k & 127;
        v = w2[((long)(t * 128 + c)) * 128 + o];
    } else {
        v = root2[(long)(k - NREL * 128) * 128 + o];
    }
    wcat[idx] = __float2bfloat16(v);
}

// ------------------------------------------------------------- launch ----
extern "C" void kernel_launch(void* const* d_in, const int* in_sizes, int n_in,
                              void* d_out, int out_size, void* d_ws,
                              size_t ws_size, hipStream_t stream)
{
    const float* feature = (const float*)d_in[0];
    const int*   eidx    = (const int*)d_in[1];
    const int*   etype   = (const int*)d_in[2];
    const float* w1      = (const float*)d_in[3];
    const float* root1   = (const float*)d_in[4];
    const float* b1      = (const float*)d_in[5];
    const float* w2      = (const float*)d_in[6];
    const float* root2   = (const float*)d_in[7];
    const float* b2      = (const float*)d_in[8];

    const int N = in_sizes[0] / IN_DIM;   // 50000
    const int E = in_sizes[2];            // 800000
    const int* esrc = eidx;
    const int* edst = eidx + E;
    const int NMT = (N + 127) / 128;      // 391
    const int NP  = NMT * 128;            // 50048

    char* p = (char*)d_ws;
    auto carve = [&](size_t b) { char* q = p; p += (b + 255) & ~(size_t)255; return q; };
    float* counts   = (float*)carve((size_t)N * NREL * 4);          // 1.6 MB
    bf16*  fb       = (bf16*)carve((size_t)NP * IN_DIM * 2);        // 76.9 MB
    bf16*  w1m      = (bf16*)carve((size_t)NTL * 128 * IN_DIM * 2); // 1.8 MB
    bf16*  wcat     = (bf16*)carve((size_t)128 * LDH * 2);          // 0.3 MB
    int*   rowstart = (int*)carve((size_t)(N + 1) * 4);
    int*   cursor   = (int*)carve((size_t)N * 4);
    int*   partials = (int*)carve(1024);
    int*   epack    = (int*)carve((size_t)E * 4);                   // 3.2 MB
    bf16*  h        = (bf16*)carve((size_t)NP * LDH * 2);           // 115.3 MB
    (void)ws_size;  // total ~200 MB; >=225 MB proven available in R2

    const int count_blks = (E + 255) / 256;
    const int nblk       = (N + 255) / 256;
    const int gat_blks   = (N * 64 + 255) / 256;   // 12500
    const int gemm_blks  = NMT * NTL;              // 3519

    // conversions (feature cvt fused with out[:, :768] copy)
    cvt_copy<<<(N * (IN_DIM / 8) + 255) / 256, 256, 0, stream>>>(
        feature, fb, (float*)d_out, N);
    {
        const long t1 = (long)NTL * 128 * IN_DIM;
        cvt_w1m<<<(int)((t1 + 255) / 256), 256, 0, stream>>>(
            w1, root1, w1m, IN_DIM, t1);
        cvt_wcat<<<(128 * LDH + 255) / 256, 256, 0, stream>>>(w2, root2, wcat);
    }

    // counts + CSR (shared by both layers)
    hipMemsetAsync(counts, 0, (size_t)N * NREL * 4, stream);
    rgcn_count<<<count_blks, 256, 0, stream>>>(edst, etype, E, counts);
    deg_block_scan<<<nblk, 256, 0, stream>>>(counts, N, rowstart, partials);
    scan_partials<<<1, 256, 0, stream>>>(partials, nblk);
    add_base<<<nblk, 256, 0, stream>>>(rowstart, partials, cursor, N, E);
    csr_fill<<<count_blks, 256, 0, stream>>>(esrc, edst, etype, E,
                                             rowstart, cursor, epack);

    // ---------------- layer 1 ----------------
    mfma_gemm<<<gemm_blks, 256, 0, stream>>>(fb, IN_DIM, w1m, h,
                                             IN_DIM, NMT, NTL);
    rgcn_gather_h<<<gat_blks, 256, 0, stream>>>(rowstart, epack, counts,
                                                h, b1, N);

    // ---------------- layer 2 ----------------
    rgcn_gather_x<<<gat_blks, 256, 0, stream>>>(rowstart, epack, counts,
                                                h, N);
    gemm_out<<<NMT, 256, 0, stream>>>(h, wcat, b2, (float*)d_out, N,
                                      LDH, NMT);
}